// Round 6
// baseline (709.426 us; speedup 1.0000x reference)
//
#include <hip/hip_runtime.h>
#include <stdint.h>

#define DEVI __device__ __forceinline__

using bf16x8 = __attribute__((ext_vector_type(8))) __bf16;
using f32x4  = __attribute__((ext_vector_type(4))) float;

DEVI ushort f2bf(float f){
  uint32_t u = __float_as_uint(f);
  uint32_t r = u + 0x7fffu + ((u >> 16) & 1u);   // RNE
  return (ushort)(r >> 16);
}
DEVI float bf2f(ushort h){ return __uint_as_float(((uint32_t)h) << 16); }

// async 16B global -> LDS (used only by the fused Sc+softmax path)
DEVI void async16(const ushort* g, ushort* l, int lbyte) {
  __builtin_amdgcn_global_load_lds(
      (const __attribute__((address_space(1))) uint32_t*)g,
      (__attribute__((address_space(3))) uint32_t*)((char*)l + lbyte),
      16, 0, 0);
}

// ---------------------------------------------------------------------------
// Segmented mega-GEMM, BARRIER-FREE direct-from-global MFMA operands.
// NT GEMM: D[m,n] = sum_k A[m,k]*B[n,k]; A,B fragments are K-contiguous 16B
// runs in global memory -> load straight into VGPRs, double-buffered; no LDS,
// no __syncthreads, compiler emits fine-grained vmcnt(N) on register deps.
// flags: 1=relu 2=out_bf16 4=src_bf16 8=src_f32 16=dual 64=Sc+softmax
// ---------------------------------------------------------------------------
struct Seg {
  const ushort* A; const ushort* B; const void* Src; void* O;
  long long sA, sB, sS, sO;
  int lda, ldb, ldS, ldc;
  int K, nbx, nbxy, flags;
  long long A2off, B2off;
};

__global__ __launch_bounds__(256, 2)
void mega(Seg s0, Seg s1, Seg s2, int n0, int n01)
{
  extern __shared__ __align__(16) ushort lds[];
  int bid = blockIdx.x;
  const Seg& s = (bid < n0) ? s0 : ((bid < n01) ? s1 : s2);
  if (bid >= n0) bid -= (bid < n01) ? n0 : n01;

  const int t = threadIdx.x;
  const int lane = t & 63, wave = t >> 6;
  const int lr = lane & 15, lq = lane >> 4;

  if (s.flags & 64) {
    // ---- fused Sc + row softmax: tile 64(M) x 256(N), in-register softmax ----
    const int lb0 = __builtin_amdgcn_readfirstlane((t & 192) * 16);
    const int niter = s.K >> 5;
    const int z = bid >> 2, mb = bid & 3;
    const ushort* pa = s.A + (long long)z*s.sA + (long long)(mb*64 + (t >> 2))*s.lda + (t & 3)*8;
    const ushort* pb = s.B + (long long)z*s.sB + (long long)(t >> 2)*s.ldb + (t & 3)*8;
    const long long b64 = 64ll*s.ldb;

    f32x4 acc[16] = {};
#define ISSUE_S(idx) { const int _i=(idx); const int _o=(_i&1)*20480 + lb0;      \
    const int _k=_i<<5;                                                          \
    async16(pa + _k, lds, _o);                                                   \
    async16(pb + _k,        lds, _o + 4096);                                     \
    async16(pb + b64 + _k,  lds, _o + 8192);                                     \
    async16(pb + 2*b64 + _k,lds, _o + 12288);                                    \
    async16(pb + 3*b64 + _k,lds, _o + 16384); }
    ISSUE_S(0);
    for (int i = 0; i < niter; ++i) {
      __syncthreads();
      if (i + 1 < niter) ISSUE_S(i + 1);
      const ushort* LA = lds + (i & 1)*10240;
      const ushort* LB = LA + 2048;
      const bf16x8 af = *(const bf16x8*)&LA[(wave*16 + lr)*32 + lq*8];
      #pragma unroll
      for (int j = 0; j < 16; j++) {
        const bf16x8 bfr = *(const bf16x8*)&LB[(j*16 + lr)*32 + lq*8];
        acc[j] = __builtin_amdgcn_mfma_f32_16x16x32_bf16(af, bfr, acc[j], 0, 0, 0);
      }
    }
    float mx[4] = {-1e30f, -1e30f, -1e30f, -1e30f};
    #pragma unroll
    for (int j = 0; j < 16; j++)
      #pragma unroll
      for (int r = 0; r < 4; r++) mx[r] = fmaxf(mx[r], acc[j][r]);
    #pragma unroll
    for (int r = 0; r < 4; r++)
      #pragma unroll
      for (int off = 1; off <= 8; off <<= 1) mx[r] = fmaxf(mx[r], __shfl_xor(mx[r], off, 64));
    float sm[4] = {0.f, 0.f, 0.f, 0.f};
    #pragma unroll
    for (int j = 0; j < 16; j++)
      #pragma unroll
      for (int r = 0; r < 4; r++) { float e = __expf(acc[j][r] - mx[r]); acc[j][r] = e; sm[r] += e; }
    #pragma unroll
    for (int r = 0; r < 4; r++) {
      #pragma unroll
      for (int off = 1; off <= 8; off <<= 1) sm[r] += __shfl_xor(sm[r], off, 64);
      sm[r] = 1.0f / sm[r];
    }
    ushort* Oz = (ushort*)s.O + (long long)z*s.sO;
    #pragma unroll
    for (int j = 0; j < 16; j++)
      #pragma unroll
      for (int r = 0; r < 4; r++) {
        const int row = mb*64 + wave*16 + lq*4 + r;
        Oz[(long long)row*s.ldc + j*16 + lr] = f2bf(acc[j][r]*sm[r]);
      }
    return;
  }

  // ---- GEMM path: barrier-free, operands direct from global ----
  const int z  = bid / s.nbxy;
  const int rz = bid % s.nbxy;
  const int bx = rz % s.nbx, by = rz / s.nbx;
  const int wm = (wave >> 1)*64, wn = (wave & 1)*64;

  const int npass = (s.flags & 16) ? 2 : 1;
  f32x4 acc[4][4] = {};
  uint pk[4][4][2];

#define LOADF(Ad, Bd, kk) { _Pragma("unroll") for (int q = 0; q < 4; q++) {      \
    Ad[q] = *(const bf16x8*)(ap[q] + (kk));                                      \
    Bd[q] = *(const bf16x8*)(bp[q] + (kk)); } }
#define MFMA16(Aa, Bb) { _Pragma("unroll") for (int x = 0; x < 4; x++)           \
    _Pragma("unroll") for (int y = 0; y < 4; y++)                                \
      acc[x][y] = __builtin_amdgcn_mfma_f32_16x16x32_bf16(Aa[x], Bb[y], acc[x][y], 0, 0, 0); }

  for (int p = 0; p < npass; ++p) {
    const ushort* Az = s.A + (p ? s.A2off : 0) + (long long)z*s.sA;
    const ushort* Bz = s.B + (p ? s.B2off : 0) + (long long)z*s.sB;
    const ushort* ap[4]; const ushort* bp[4];
    #pragma unroll
    for (int q = 0; q < 4; q++) {
      ap[q] = Az + (long long)(by*128 + wm + q*16 + lr)*s.lda + lq*8;
      bp[q] = Bz + (long long)(bx*128 + wn + q*16 + lr)*s.ldb + lq*8;
    }
    bf16x8 a0[4], b0[4], a1[4], b1[4];
    LOADF(a0, b0, 0);
    const int K = s.K;
    for (int k0 = 0; k0 < K; k0 += 64) {
      LOADF(a1, b1, k0 + 32);
      MFMA16(a0, b0);
      if (k0 + 64 < K) LOADF(a0, b0, k0 + 64);
      MFMA16(a1, b1);
    }
    if (p == 0 && npass == 2) {   // stash relu(pass0) packed bf16, reset acc
      #pragma unroll
      for (int x = 0; x < 4; x++)
        #pragma unroll
        for (int y = 0; y < 4; y++) {
          pk[x][y][0] = (uint)f2bf(fmaxf(acc[x][y][0], 0.0f)) | ((uint)f2bf(fmaxf(acc[x][y][1], 0.0f)) << 16);
          pk[x][y][1] = (uint)f2bf(fmaxf(acc[x][y][2], 0.0f)) | ((uint)f2bf(fmaxf(acc[x][y][3], 0.0f)) << 16);
          acc[x][y] = (f32x4){0.f, 0.f, 0.f, 0.f};
        }
    }
  }

  // epilogue: D row = (lane>>4)*4 + reg, col = lane&15
  const int rowb = by*128 + wm + lq*4;
  const int colb = bx*128 + wn + lr;
  const int fl = s.flags;
  #pragma unroll
  for (int x = 0; x < 4; x++) {
    #pragma unroll
    for (int y = 0; y < 4; y++) {
      const int col = colb + y*16;
      #pragma unroll
      for (int r = 0; r < 4; r++) {
        const int row = rowb + x*16 + r;
        float v = acc[x][y][r];
        if (fl & 1)  v = fmaxf(v, 0.0f);
        if (fl & 16) v += bf2f((ushort)(pk[x][y][r >> 1] >> (16*(r & 1))));
        if (fl & 4)  v += bf2f(((const ushort*)s.Src)[(long long)z*s.sS + (long long)row*s.ldS + col]);
        if (fl & 8)  v += ((const float*)s.Src)[(long long)z*s.sS + (long long)row*s.ldS + col];
        if (fl & 2)
          ((ushort*)s.O)[(long long)z*s.sO + (long long)row*s.ldc + col] = f2bf(v);
        else
          ((float*)s.O)[(long long)z*s.sO + (long long)row*s.ldc + col] = v;
      }
    }
  }
}

// ---------------------------------------------------------------------------
// fused prep: [0,8192) cast f -> bf16 ; [8192,11008) 11 weight transposes ;
// [11008,15104) adj -> adj/adjT bf16
// ---------------------------------------------------------------------------
struct P11 { const float* p[11]; };

__global__ void prep(const float* __restrict__ F, ushort* __restrict__ FB,
                     P11 ps, ushort* __restrict__ WT,
                     const float* __restrict__ ADJ, ushort* __restrict__ AB,
                     ushort* __restrict__ ATB)
{
  __shared__ float tile[32][33];
  const int b = blockIdx.x, t = threadIdx.x;
  if (b < 8192) {
    const int i = b*256 + t;
    const float4 v = ((const float4*)F)[i];
    ushort4 o; o.x = f2bf(v.x); o.y = f2bf(v.y); o.z = f2bf(v.z); o.w = f2bf(v.w);
    ((ushort4*)FB)[i] = o;
  } else if (b < 11008) {
    const int q = b - 8192;
    const int wdx = q >> 8, tl = q & 255;
    const int bo = (tl & 15)*32, bk = (tl >> 4)*32;
    const int tx = t & 31, ty = t >> 5;
    const float* in = ps.p[wdx];
    ushort* o = WT + (long long)wdx*262144;
    #pragma unroll
    for (int r = 0; r < 32; r += 8) tile[ty+r][tx] = in[(long long)(bk+ty+r)*512 + bo+tx];
    __syncthreads();
    #pragma unroll
    for (int r = 0; r < 32; r += 8) o[(long long)(bo+ty+r)*512 + bk+tx] = f2bf(tile[tx][ty+r]);
  } else {
    const int q = b - 11008;
    const long long base = (long long)(q >> 6)*65536;
    const int bi = ((q >> 3) & 7)*32, bj = (q & 7)*32;
    const int tx = t & 31, ty = t >> 5;
    #pragma unroll
    for (int r = 0; r < 32; r += 8) {
      const float v = ADJ[base + (long long)(bi+ty+r)*256 + bj+tx];
      tile[ty+r][tx] = v;
      AB[base + (long long)(bi+ty+r)*256 + bj+tx] = f2bf(v);
    }
    __syncthreads();
    #pragma unroll
    for (int r = 0; r < 32; r += 8)
      ATB[base + (long long)(bj+ty+r)*256 + bi+tx] = f2bf(tile[tx][ty+r]);
  }
}

// ---------------------------------------------------------------------------
extern "C" void kernel_launch(void* const* d_in, const int* in_sizes, int n_in,
                              void* d_out, int out_size, void* d_ws, size_t ws_size,
                              hipStream_t stream)
{
  (void)in_sizes; (void)n_in; (void)out_size;
  const float* F   = (const float*)d_in[0];
  const float* ADJ = (const float*)d_in[2];

  uint8_t* w = (uint8_t*)d_ws;
  size_t off = 0;
  auto alloc = [&](size_t bytes) -> void* { void* p = w + off; off += (bytes + 255) & ~(size_t)255; return p; };

  const long long SL = 262144;
  ushort* WT   = (ushort*)alloc(11*524288);  // 0:Wst1 1:Wst1b 2:Wst2 3:Wst2b 4:Wst3 5:Wst3b 6-8:Wsim1-3 9:Wse1T 10:Wse2T
  ushort* WMT  = (ushort*)alloc(524288);
  ushort* FB   = (ushort*)alloc(16777216);
  ushort* ADJB = (ushort*)alloc(8388608);
  ushort* ADJT = (ushort*)alloc(8388608);
  ushort* TB   = (ushort*)alloc(16777216);
  ushort* Sb   = (ushort*)alloc(8388608);
  ushort* YTB  = (ushort*)alloc(33554432);
  ushort* SY   = (ushort*)alloc(16777216);
  ushort* Gb   = (ushort*)alloc(16777216);
  ushort* Hb   = (ushort*)alloc(16777216);
  if (off > ws_size) return;

  const long long sNC = 131072, sNN = 65536, sYT = 262144, sSY = 131072;

  auto mk = [](const void* A, long long sA, int lda, const void* B, long long sB, int ldb,
               const void* Src, long long sS, int ldS, void* O, long long sO, int ldc,
               int K, int M, int Nn, int flags, long long A2off, long long B2off) -> Seg {
    Seg s; s.A = (const ushort*)A; s.B = (const ushort*)B; s.Src = Src; s.O = O;
    s.sA = sA; s.sB = sB; s.sS = sS; s.sO = sO;
    s.lda = lda; s.ldb = ldb; s.ldS = ldS; s.ldc = ldc;
    s.K = K; s.nbx = Nn/128; s.nbxy = (Nn/128)*(M/128); s.flags = flags;
    s.A2off = A2off; s.B2off = B2off; return s;
  };
  auto L1 = [&](const Seg& a, int na, int lb) { mega<<<na, 256, lb, stream>>>(a, a, a, na, na); };
  auto L2 = [&](const Seg& a, int na, const Seg& b, int nb, int lb) {
    mega<<<na+nb, 256, lb, stream>>>(a, b, b, na, na+nb); };
  auto L3 = [&](const Seg& a, int na, const Seg& b, int nb, const Seg& c, int nc, int lb) {
    mega<<<na+nb+nc, 256, lb, stream>>>(a, b, c, na, na+nb); };

  // ---- D1: fused prep ----
  P11 ps;
  ps.p[0] = (const float*)d_in[5];  ps.p[1] = (const float*)d_in[8];
  ps.p[2] = (const float*)d_in[6];  ps.p[3] = (const float*)d_in[9];
  ps.p[4] = (const float*)d_in[7];  ps.p[5] = (const float*)d_in[10];
  ps.p[6] = (const float*)d_in[11]; ps.p[7] = (const float*)d_in[12];
  ps.p[8] = (const float*)d_in[13];
  ps.p[9] = (const float*)d_in[3];  ps.p[10] = (const float*)d_in[4];
  prep<<<15104, 256, 0, stream>>>(F, FB, ps, WT, ADJ, ADJB, ADJT);

  const long long dA = (long long)(ADJT - ADJB);

  Seg Wmid = mk(WT+10*SL,0,512, WT+9*SL,0,512, nullptr,0,0, WMT,0,512, 512, 512,512, 2, 0,0);
  Seg Z1   = mk(WT+0*SL,0,512, FB,sNC,512, nullptr,0,0, YTB,sYT,256, 512, 1024,256, 2, 0,0);
  Seg Y1   = mk(WT+6*SL,0,512, FB,sNC,512, nullptr,0,0, SY,sSY,256, 512, 512,256, 2, 0,0);
  Seg Tsg  = mk(FB,sNC,512, WMT,0,512, nullptr,0,0, TB,sNC,512, 512, 256,512, 2, 0,0);
  Seg H1   = mk(ADJB,sNN,256, YTB,sYT,256, nullptr,0,0, Hb,sNC,512, 256, 256,512, 1|2|16, dA,131072);
  Seg ScS; ScS.A = TB; ScS.B = FB; ScS.Src = nullptr; ScS.O = Sb;
  ScS.sA = sNC; ScS.sB = sNC; ScS.sS = 0; ScS.sO = sNN;
  ScS.lda = 512; ScS.ldb = 512; ScS.ldS = 0; ScS.ldc = 256;
  ScS.K = 512; ScS.nbx = 1; ScS.nbxy = 4; ScS.flags = 64; ScS.A2off = 0; ScS.B2off = 0;
  Seg Z2   = mk(WT+2*SL,0,512, Hb,sNC,512, nullptr,0,0, YTB,sYT,256, 512, 1024,256, 2, 0,0);
  Seg H2   = H1;
  Seg G1   = mk(Sb,sNN,256, SY,sSY,256, nullptr,0,0, Gb,sNC,512, 256, 256,512, 1|2, 0,0);
  Seg Z3   = mk(WT+4*SL,0,512, Hb,sNC,512, nullptr,0,0, YTB,sYT,256, 512, 1024,256, 2, 0,0);
  Seg Y2   = mk(WT+7*SL,0,512, Gb,sNC,512, nullptr,0,0, SY,sSY,256, 512, 512,256, 2, 0,0);
  Seg H3   = H1;
  Seg G2   = G1;
  Seg Y3   = mk(WT+8*SL,0,512, Gb,sNC,512, nullptr,0,0, SY,sSY,256, 512, 512,256, 2, 0,0);
  Seg Fin  = mk(Sb,sNN,256, SY,sSY,256, Hb,sNC,512, d_out,sNC,512, 256, 256,512, 1|4, 0,0);

  // ---- schedule: sim chain (T,ScS,G1,Y2,G2,Y3,Fin) || st chain (Z1,H1..H3)
  L3(Wmid,16, Z1,1024, Y1,512, 0);   // D2
  L2(Tsg,512, H1,512, 0);            // D3
  L2(ScS,256, Z2,1024, 40960);       // D4
  L2(G1,512,  H2,512, 0);            // D5
  L2(Y2,512,  Z3,1024, 0);           // D6
  L2(G2,512,  H3,512, 0);            // D7
  L1(Y3,512, 0);                     // D8
  L1(Fin,512, 0);                    // D9
}

// Round 7
// 389.010 us; speedup vs baseline: 1.8237x; 1.8237x over previous
//
#include <hip/hip_runtime.h>
#include <stdint.h>

#define DEVI __device__ __forceinline__

using bf16x8 = __attribute__((ext_vector_type(8))) __bf16;
using f32x4  = __attribute__((ext_vector_type(4))) float;

DEVI ushort f2bf(float f){
  uint32_t u = __float_as_uint(f);
  uint32_t r = u + 0x7fffu + ((u >> 16) & 1u);   // RNE
  return (ushort)(r >> 16);
}
DEVI float bf2f(ushort h){ return __uint_as_float(((uint32_t)h) << 16); }

// async 16B global -> LDS (wave-uniform LDS base; lane lands at base + lane*16)
DEVI void async16(const ushort* g, ushort* l, int lbyte) {
  __builtin_amdgcn_global_load_lds(
      (const __attribute__((address_space(1))) uint32_t*)g,
      (__attribute__((address_space(3))) uint32_t*)((char*)l + lbyte),
      16, 0, 0);
}

// ---------------------------------------------------------------------------
// Segmented mega kernel. Paths:
//  flags&128: FUSED GCN LAYER  out = relu(G @ (X @ Wslab)) [+ dual branch]
//             block = (z, 64-col slab); phase1 Y=X@Wslab -> LDS (transposed,
//             stride 264); phase2 G@Y with B-frags from LDS. Y never hits HBM.
//  flags&64 : fused Sc + row softmax
//  else     : plain NT GEMM 128x128 tile, LDS-staged (round-2 structure)
// flags: 1=relu 2=out_bf16 4=add Src2 bf16 16=dual 64=ScS 128=fused layer
// ---------------------------------------------------------------------------
struct Seg {
  const ushort* A; const ushort* B; const void* Src; const void* Src2; void* O;
  long long sA, sB, sS, sS2, sO;
  int lda, ldb, ldS, ldS2, ldc;
  int K, nbx, nbxy, flags;
  long long A2off, B2off;
};

__global__ __launch_bounds__(256, 2)
void mega(Seg s0, Seg s1, Seg s2, int n0s, int n01)
{
  extern __shared__ __align__(16) ushort lds[];
  int bid = blockIdx.x;
  const Seg& s = (bid < n0s) ? s0 : ((bid < n01) ? s1 : s2);
  if (bid >= n0s) bid -= (bid < n01) ? n0s : n01;

  const int t = threadIdx.x;
  const int lane = t & 63, wave = t >> 6;
  const int lr = lane & 15, lq = lane >> 4;
  const int lb0 = __builtin_amdgcn_readfirstlane((t & 192) * 16);

#define MFMA16(Aa, Bb) { _Pragma("unroll") for (int x = 0; x < 4; x++)           \
    _Pragma("unroll") for (int y = 0; y < 4; y++)                                \
      acc[x][y] = __builtin_amdgcn_mfma_f32_16x16x32_bf16(Aa[x], Bb[y], acc[x][y], 0, 0, 0); }

  if (s.flags & 128) {
    // ================= fused GCN layer =================
    const int z    = (bid & 7) + ((bid >> 6) << 3);   // XCD swizzle: same z -> same XCD
    const int slab = (bid >> 3) & 7;
    const int n0   = slab * 64;

    ushort* Yt  = lds;            // 64 cols x 264 (256 rows + pad), bf16
    ushort* stA = lds + 16896;    // 256 x 32 staging (X / G tiles)
    ushort* stW = lds + 25088;    // 64 x 32 staging (W slab tile)

    const int r0 = t >> 2, c0 = (t & 3) * 8;

    const ushort* X  = s.A + (long long)z * s.sA;
    const ushort* Wf = s.B + (long long)n0 * 512;
    const ushort* G0 = (const ushort*)s.Src + (long long)z * s.sS;

    f32x4 acc[4][4] = {};
    uint pk[4][4][2];
    const int npass = (s.flags & 16) ? 2 : 1;

    for (int p = 0; p < npass; ++p) {
      const ushort* Wp = p ? (Wf + s.B2off) : Wf;
      const ushort* Gp = p ? (G0 + s.A2off) : G0;
      const ushort* pX = X  + (long long)r0 * 512 + c0;
      const ushort* pW = Wp + (long long)r0 * 512 + c0;

      // ---- phase 1: Y(256x64) = X @ Wslab  (NT, K=512) ----
      for (int k0 = 0; k0 < 512; k0 += 32) {
        __syncthreads();
        #pragma unroll
        for (int i = 0; i < 4; i++)
          async16(pX + (long long)(64*i)*512 + k0, stA, i*4096 + lb0);
        async16(pW + k0, stW, lb0);
        __syncthreads();
        bf16x8 af[4], bw[4];
        #pragma unroll
        for (int x = 0; x < 4; x++)
          af[x] = *(const bf16x8*)&stA[(64*wave + x*16 + lr)*32 + lq*8];
        #pragma unroll
        for (int y = 0; y < 4; y++)
          bw[y] = *(const bf16x8*)&stW[(y*16 + lr)*32 + lq*8];
        MFMA16(af, bw);
      }
      __syncthreads();   // all ph1 LDS reads done before Yt overwrite below
      // dump Y -> Yt transposed (bf16), reset acc
      #pragma unroll
      for (int x = 0; x < 4; x++)
        #pragma unroll
        for (int y = 0; y < 4; y++) {
          const int col  = y*16 + lr;
          const int rowb = 64*wave + x*16 + lq*4;
          uint2 v;
          v.x = (uint)f2bf(acc[x][y][0]) | ((uint)f2bf(acc[x][y][1]) << 16);
          v.y = (uint)f2bf(acc[x][y][2]) | ((uint)f2bf(acc[x][y][3]) << 16);
          *(uint2*)&Yt[col*264 + rowb] = v;
          acc[x][y] = (f32x4){0.f, 0.f, 0.f, 0.f};
        }
      // ---- phase 2: acc = G(256x256) @ Y  (B-frags from Yt) ----
      const ushort* pG = Gp + (long long)r0 * s.ldS + c0;
      for (int k0 = 0; k0 < 256; k0 += 32) {
        __syncthreads();   // first iter: also covers Yt writes
        #pragma unroll
        for (int i = 0; i < 4; i++)
          async16(pG + (long long)(64*i)*s.ldS + k0, stA, i*4096 + lb0);
        __syncthreads();
        bf16x8 af[4], bfr[4];
        #pragma unroll
        for (int x = 0; x < 4; x++)
          af[x] = *(const bf16x8*)&stA[(64*wave + x*16 + lr)*32 + lq*8];
        #pragma unroll
        for (int y = 0; y < 4; y++)
          bfr[y] = *(const bf16x8*)&Yt[(y*16 + lr)*264 + k0 + lq*8];
        MFMA16(af, bfr);
      }
      if (p == 0 && npass == 2) {   // stash relu(forward branch) packed bf16
        #pragma unroll
        for (int x = 0; x < 4; x++)
          #pragma unroll
          for (int y = 0; y < 4; y++) {
            pk[x][y][0] = (uint)f2bf(fmaxf(acc[x][y][0],0.f)) | ((uint)f2bf(fmaxf(acc[x][y][1],0.f)) << 16);
            pk[x][y][1] = (uint)f2bf(fmaxf(acc[x][y][2],0.f)) | ((uint)f2bf(fmaxf(acc[x][y][3],0.f)) << 16);
            acc[x][y] = (f32x4){0.f, 0.f, 0.f, 0.f};
          }
      }
    }
    // epilogue: row = 64*wave + x*16 + lq*4 + r, col = n0 + y*16 + lr
    const int fl = s.flags;
    #pragma unroll
    for (int x = 0; x < 4; x++)
      #pragma unroll
      for (int y = 0; y < 4; y++) {
        const int col = n0 + y*16 + lr;
        #pragma unroll
        for (int r = 0; r < 4; r++) {
          const int row = 64*wave + x*16 + lq*4 + r;
          float v = fmaxf(acc[x][y][r], 0.f);
          if (fl & 16) v += bf2f((ushort)(pk[x][y][r >> 1] >> (16*(r & 1))));
          if (fl & 4)  v += bf2f(((const ushort*)s.Src2)[(long long)z*s.sS2 + (long long)row*s.ldS2 + col]);
          if (fl & 2)
            ((ushort*)s.O)[(long long)z*s.sO + (long long)row*s.ldc + col] = f2bf(v);
          else
            ((float*)s.O)[(long long)z*s.sO + (long long)row*s.ldc + col] = v;
        }
      }
    return;
  }

  if (s.flags & 64) {
    // ================= fused Sc + row softmax =================
    const int niter = s.K >> 5;
    const int z = bid >> 2, mb = bid & 3;
    const ushort* pa = s.A + (long long)z*s.sA + (long long)(mb*64 + (t >> 2))*s.lda + (t & 3)*8;
    const ushort* pb = s.B + (long long)z*s.sB + (long long)(t >> 2)*s.ldb + (t & 3)*8;
    const long long b64 = 64ll*s.ldb;

    f32x4 acc[16] = {};
#define ISSUE_S(idx) { const int _i=(idx); const int _o=(_i&1)*20480 + lb0;      \
    const int _k=_i<<5;                                                          \
    async16(pa + _k, lds, _o);                                                   \
    async16(pb + _k,        lds, _o + 4096);                                     \
    async16(pb + b64 + _k,  lds, _o + 8192);                                     \
    async16(pb + 2*b64 + _k,lds, _o + 12288);                                    \
    async16(pb + 3*b64 + _k,lds, _o + 16384); }
    ISSUE_S(0);
    for (int i = 0; i < niter; ++i) {
      __syncthreads();
      if (i + 1 < niter) ISSUE_S(i + 1);
      const ushort* LA = lds + (i & 1)*10240;
      const ushort* LB = LA + 2048;
      const bf16x8 af = *(const bf16x8*)&LA[(wave*16 + lr)*32 + lq*8];
      #pragma unroll
      for (int j = 0; j < 16; j++) {
        const bf16x8 bfr = *(const bf16x8*)&LB[(j*16 + lr)*32 + lq*8];
        acc[j] = __builtin_amdgcn_mfma_f32_16x16x32_bf16(af, bfr, acc[j], 0, 0, 0);
      }
    }
    float mx[4] = {-1e30f, -1e30f, -1e30f, -1e30f};
    #pragma unroll
    for (int j = 0; j < 16; j++)
      #pragma unroll
      for (int r = 0; r < 4; r++) mx[r] = fmaxf(mx[r], acc[j][r]);
    #pragma unroll
    for (int r = 0; r < 4; r++)
      #pragma unroll
      for (int off = 1; off <= 8; off <<= 1) mx[r] = fmaxf(mx[r], __shfl_xor(mx[r], off, 64));
    float sm[4] = {0.f, 0.f, 0.f, 0.f};
    #pragma unroll
    for (int j = 0; j < 16; j++)
      #pragma unroll
      for (int r = 0; r < 4; r++) { float e = __expf(acc[j][r] - mx[r]); acc[j][r] = e; sm[r] += e; }
    #pragma unroll
    for (int r = 0; r < 4; r++) {
      #pragma unroll
      for (int off = 1; off <= 8; off <<= 1) sm[r] += __shfl_xor(sm[r], off, 64);
      sm[r] = 1.0f / sm[r];
    }
    ushort* Oz = (ushort*)s.O + (long long)z*s.sO;
    #pragma unroll
    for (int j = 0; j < 16; j++)
      #pragma unroll
      for (int r = 0; r < 4; r++) {
        const int row = mb*64 + wave*16 + lq*4 + r;
        Oz[(long long)row*s.ldc + j*16 + lr] = f2bf(acc[j][r]*sm[r]);
      }
    return;
  }

  // ================= plain NT GEMM (round-2 structure) =================
  {
    ushort* lA = lds;          // 128 x 32
    ushort* lB = lds + 4096;   // 128 x 32
    const int z  = bid / s.nbxy;
    const int rz = bid % s.nbxy;
    const int bx = rz % s.nbx, by = rz / s.nbx;
    const int wm = (wave >> 1)*64, wn = (wave & 1)*64;
    const int r0 = t >> 2, c0 = (t & 3)*8;

    const ushort* pa = s.A + (long long)z*s.sA + (long long)(by*128 + r0)*s.lda + c0;
    const ushort* pb = s.B + (long long)z*s.sB + (long long)(bx*128 + r0)*s.ldb + c0;
    const long long a64 = 64ll*s.lda, b64 = 64ll*s.ldb;

    f32x4 acc[4][4] = {};
    for (int k0 = 0; k0 < s.K; k0 += 32) {
      __syncthreads();
      async16(pa + k0,       lA, lb0);
      async16(pa + a64 + k0, lA, lb0 + 4096);
      async16(pb + k0,       lB, lb0);
      async16(pb + b64 + k0, lB, lb0 + 4096);
      __syncthreads();
      bf16x8 af[4], bfr[4];
      #pragma unroll
      for (int x = 0; x < 4; x++) {
        af[x]  = *(const bf16x8*)&lA[(wm + x*16 + lr)*32 + lq*8];
        bfr[x] = *(const bf16x8*)&lB[(wn + x*16 + lr)*32 + lq*8];
      }
      MFMA16(af, bfr);
    }
    const int rowb = by*128 + wm + lq*4;
    const int colb = bx*128 + wn + lr;
    const int fl = s.flags;
    #pragma unroll
    for (int x = 0; x < 4; x++)
      #pragma unroll
      for (int y = 0; y < 4; y++) {
        const int col = colb + y*16;
        #pragma unroll
        for (int r = 0; r < 4; r++) {
          const int row = rowb + x*16 + r;
          float v = acc[x][y][r];
          if (fl & 1) v = fmaxf(v, 0.f);
          if (fl & 2)
            ((ushort*)s.O)[(long long)z*s.sO + (long long)row*s.ldc + col] = f2bf(v);
          else
            ((float*)s.O)[(long long)z*s.sO + (long long)row*s.ldc + col] = v;
        }
      }
  }
}

// ---------------------------------------------------------------------------
// fused prep: [0,8192) cast f -> bf16 ; [8192,11008) 11 weight transposes ;
// [11008,15104) adj -> adj/adjT bf16
// ---------------------------------------------------------------------------
struct P11 { const float* p[11]; };

__global__ void prep(const float* __restrict__ F, ushort* __restrict__ FB,
                     P11 ps, ushort* __restrict__ WT,
                     const float* __restrict__ ADJ, ushort* __restrict__ AB,
                     ushort* __restrict__ ATB)
{
  __shared__ float tile[32][33];
  const int b = blockIdx.x, t = threadIdx.x;
  if (b < 8192) {
    const int i = b*256 + t;
    const float4 v = ((const float4*)F)[i];
    ushort4 o; o.x = f2bf(v.x); o.y = f2bf(v.y); o.z = f2bf(v.z); o.w = f2bf(v.w);
    ((ushort4*)FB)[i] = o;
  } else if (b < 11008) {
    const int q = b - 8192;
    const int wdx = q >> 8, tl = q & 255;
    const int bo = (tl & 15)*32, bk = (tl >> 4)*32;
    const int tx = t & 31, ty = t >> 5;
    const float* in = ps.p[wdx];
    ushort* o = WT + (long long)wdx*262144;
    #pragma unroll
    for (int r = 0; r < 32; r += 8) tile[ty+r][tx] = in[(long long)(bk+ty+r)*512 + bo+tx];
    __syncthreads();
    #pragma unroll
    for (int r = 0; r < 32; r += 8) o[(long long)(bo+ty+r)*512 + bk+tx] = f2bf(tile[tx][ty+r]);
  } else {
    const int q = b - 11008;
    const long long base = (long long)(q >> 6)*65536;
    const int bi = ((q >> 3) & 7)*32, bj = (q & 7)*32;
    const int tx = t & 31, ty = t >> 5;
    #pragma unroll
    for (int r = 0; r < 32; r += 8) {
      const float v = ADJ[base + (long long)(bi+ty+r)*256 + bj+tx];
      tile[ty+r][tx] = v;
      AB[base + (long long)(bi+ty+r)*256 + bj+tx] = f2bf(v);
    }
    __syncthreads();
    #pragma unroll
    for (int r = 0; r < 32; r += 8)
      ATB[base + (long long)(bj+ty+r)*256 + bi+tx] = f2bf(tile[tx][ty+r]);
  }
}

// ---------------------------------------------------------------------------
extern "C" void kernel_launch(void* const* d_in, const int* in_sizes, int n_in,
                              void* d_out, int out_size, void* d_ws, size_t ws_size,
                              hipStream_t stream)
{
  (void)in_sizes; (void)n_in; (void)out_size;
  const float* F   = (const float*)d_in[0];
  const float* ADJ = (const float*)d_in[2];

  uint8_t* w = (uint8_t*)d_ws;
  size_t off = 0;
  auto alloc = [&](size_t bytes) -> void* { void* p = w + off; off += (bytes + 255) & ~(size_t)255; return p; };

  const long long SL = 262144;
  ushort* WT   = (ushort*)alloc(11*524288);  // 0:Wst1 1:Wst1b 2:Wst2 3:Wst2b 4:Wst3 5:Wst3b 6-8:Wsim1-3 9:Wse1T 10:Wse2T
  ushort* WMT  = (ushort*)alloc(524288);
  ushort* FB   = (ushort*)alloc(16777216);
  ushort* ADJB = (ushort*)alloc(8388608);
  ushort* ADJT = (ushort*)alloc(8388608);
  ushort* TB   = (ushort*)alloc(16777216);
  ushort* Sb   = (ushort*)alloc(8388608);
  ushort* Hb   = (ushort*)alloc(16777216);   // st ping
  ushort* Hb2  = (ushort*)alloc(16777216);   // st pong
  ushort* Gb   = (ushort*)alloc(16777216);   // sim ping
  ushort* Gb2  = (ushort*)alloc(16777216);   // sim pong
  if (off > ws_size) return;

  const long long sNC = 131072, sNN = 65536;
  const int LDSB = 54272;

  auto zero = [](Seg& s) {
    s.A = nullptr; s.B = nullptr; s.Src = nullptr; s.Src2 = nullptr; s.O = nullptr;
    s.sA = s.sB = s.sS = s.sS2 = s.sO = 0;
    s.lda = s.ldb = s.ldS = s.ldS2 = s.ldc = 0;
    s.K = 0; s.nbx = 1; s.nbxy = 1; s.flags = 0; s.A2off = s.B2off = 0;
  };
  auto mkP = [&](const void* A, long long sA, int lda, const void* B, long long sB, int ldb,
                 void* O, long long sO, int ldc, int K, int M, int Nn, int flags) -> Seg {
    Seg s; zero(s);
    s.A = (const ushort*)A; s.B = (const ushort*)B; s.O = O;
    s.sA = sA; s.sB = sB; s.sO = sO;
    s.lda = lda; s.ldb = ldb; s.ldc = ldc;
    s.K = K; s.nbx = Nn/128; s.nbxy = (Nn/128)*(M/128); s.flags = flags;
    return s;
  };
  auto mkF = [&](const void* X, const void* Wf, long long B2off, const void* G, long long A2off,
                 const void* Src2, void* O, int flags) -> Seg {
    Seg s; zero(s);
    s.A = (const ushort*)X; s.sA = sNC; s.lda = 512;
    s.B = (const ushort*)Wf; s.B2off = B2off;
    s.Src = G; s.sS = sNN; s.ldS = 256; s.A2off = A2off;
    s.Src2 = Src2; s.sS2 = sNC; s.ldS2 = 512;
    s.O = O; s.sO = sNC; s.ldc = 512;
    s.flags = 128 | flags;
    return s;
  };
  auto L1 = [&](const Seg& a, int na) { mega<<<na, 256, LDSB, stream>>>(a, a, a, na, na); };
  auto L2 = [&](const Seg& a, int na, const Seg& b, int nb) {
    mega<<<na+nb, 256, LDSB, stream>>>(a, b, b, na, na+nb); };

  // ---- D1: fused prep ----
  P11 ps;
  ps.p[0] = (const float*)d_in[5];  ps.p[1] = (const float*)d_in[8];
  ps.p[2] = (const float*)d_in[6];  ps.p[3] = (const float*)d_in[9];
  ps.p[4] = (const float*)d_in[7];  ps.p[5] = (const float*)d_in[10];
  ps.p[6] = (const float*)d_in[11]; ps.p[7] = (const float*)d_in[12];
  ps.p[8] = (const float*)d_in[13];
  ps.p[9] = (const float*)d_in[3];  ps.p[10] = (const float*)d_in[4];
  prep<<<15104, 256, 0, stream>>>(F, FB, ps, WT, ADJ, ADJB, ADJT);

  const long long dA = (long long)(ADJT - ADJB);

  Seg Wmid = mkP(WT+10*SL,0,512, WT+9*SL,0,512, WMT,0,512, 512, 512,512, 2);
  Seg Tsg  = mkP(FB,sNC,512, WMT,0,512, TB,sNC,512, 512, 256,512, 2);
  Seg ScS; zero(ScS);
  ScS.A = TB; ScS.B = FB; ScS.O = Sb;
  ScS.sA = sNC; ScS.sB = sNC; ScS.sO = sNN;
  ScS.lda = 512; ScS.ldb = 512; ScS.ldc = 256;
  ScS.K = 512; ScS.flags = 64;

  Seg ST1  = mkF(FB,  WT+0*SL, SL, ADJB, dA, nullptr, Hb,  16|2);
  Seg ST2  = mkF(Hb,  WT+2*SL, SL, ADJB, dA, nullptr, Hb2, 16|2);
  Seg ST3  = mkF(Hb2, WT+4*SL, SL, ADJB, dA, nullptr, Hb,  16|2);
  Seg SIM1 = mkF(FB,  WT+6*SL, 0,  Sb,   0,  nullptr, Gb,  2);
  Seg SIM2 = mkF(Gb,  WT+7*SL, 0,  Sb,   0,  nullptr, Gb2, 2);
  Seg SIM3 = mkF(Gb2, WT+8*SL, 0,  Sb,   0,  Hb,      d_out, 4);   // fp32 out = relu(S@Y3) + Hst

  // ---- schedule: st chain || sim front-end ----
  L2(Wmid,16, ST1,512);   // D2
  L2(Tsg,512, ST2,512);   // D3
  L2(ScS,256, ST3,512);   // D4
  L1(SIM1,512);           // D5
  L1(SIM2,512);           // D6
  L1(SIM3,512);           // D7
}